// Round 1
// baseline (263.679 us; speedup 1.0000x reference)
//
#include <hip/hip_runtime.h>
#include <math.h>

#define N_ROWS 262144
#define D 128
#define C 64
#define BLOCKS 512
#define THREADS 512              // 8 waves
#define WAVES (THREADS / 64)
#define ROWS_PER_BLOCK (N_ROWS / BLOCKS)      // 512
#define ROWS_PER_WAVE (ROWS_PER_BLOCK / WAVES) // 64

// ws layout (floats): [0, C*D) class sums | [C*D, C*D+C) counts
//                     | [C*D+C, C*D+2C) sumsq | [C*D+2C] ce_sum
#define WS_FLOATS (C * D + 2 * C + 1)

__global__ __launch_bounds__(THREADS) void proto_main(
    const float* __restrict__ emb, const float* __restrict__ logits,
    const int* __restrict__ labels, float* __restrict__ ws) {
  __shared__ float sSums[C * D];
  __shared__ float sCnt[C];
  __shared__ float sSq[C];
  __shared__ float sCe[WAVES];

  const int tid = threadIdx.x;
  for (int i = tid; i < C * D; i += THREADS) sSums[i] = 0.f;
  if (tid < C) { sCnt[tid] = 0.f; sSq[tid] = 0.f; }
  __syncthreads();

  const int wave = tid >> 6;
  const int lane = tid & 63;
  float ce_acc = 0.f;

  const int base = blockIdx.x * ROWS_PER_BLOCK;
  for (int it = 0; it < ROWS_PER_WAVE; ++it) {
    const int row = base + it * WAVES + wave;

    // ---- embedding row: L2 norm ----
    const float2 e2 = *(const float2*)(emb + (size_t)row * D + lane * 2);
    float ss = e2.x * e2.x + e2.y * e2.y;
#pragma unroll
    for (int off = 1; off < 64; off <<= 1) ss += __shfl_xor(ss, off);
    const float inv = 1.0f / fmaxf(sqrtf(ss), 1e-12f);
    const float z0 = e2.x * inv, z1 = e2.y * inv;
    const float zsq = ss * inv * inv;
    const int lab = labels[row];

    // ---- cross-entropy for this row ----
    const float t = logits[(size_t)row * C + lane];
    float m = t;
#pragma unroll
    for (int off = 1; off < 64; off <<= 1) m = fmaxf(m, __shfl_xor(m, off));
    float p = __expf(t - m);
#pragma unroll
    for (int off = 1; off < 64; off <<= 1) p += __shfl_xor(p, off);
    const float lse = m + __logf(p);
    const float tl = __shfl(t, lab);
    if (lane == 0) ce_acc += (lse - tl);

    // ---- per-class accumulation (LDS atomics) ----
    atomicAdd(&sSums[lab * D + lane * 2], z0);
    atomicAdd(&sSums[lab * D + lane * 2 + 1], z1);
    if (lane == 0) {
      atomicAdd(&sCnt[lab], 1.f);
      atomicAdd(&sSq[lab], zsq);
    }
  }
  if (lane == 0) sCe[wave] = ce_acc;
  __syncthreads();

  // ---- flush block partials to global accumulators ----
  // rotate start offset per block to spread atomic hotspots
  const int rot = (blockIdx.x * 1031) & (C * D - 1);
  for (int i = tid; i < C * D; i += THREADS) {
    const int j = (i + rot) & (C * D - 1);
    atomicAdd(&ws[j], sSums[j]);
  }
  if (tid < C) {
    atomicAdd(&ws[C * D + tid], sCnt[tid]);
  } else if (tid >= 64 && tid < 64 + C) {
    atomicAdd(&ws[C * D + C + (tid - 64)], sSq[tid - 64]);
  }
  if (tid == 0) {
    float s = 0.f;
    for (int w = 0; w < WAVES; ++w) s += sCe[w];
    atomicAdd(&ws[C * D + 2 * C], s);
  }
}

__global__ __launch_bounds__(256) void proto_final(const float* __restrict__ ws,
                                                   float* __restrict__ out) {
  __shared__ float sPer[C];
  __shared__ float sValid[C];
  const int tid = threadIdx.x;  // 256 threads = 4 waves
  const int wave = tid >> 6, lane = tid & 63;

  for (int c = wave; c < C; c += 4) {
    const float n = ws[C * D + c];
    const float safe = fmaxf(n, 1.f);
    const float s0 = ws[c * D + lane];
    const float s1 = ws[c * D + 64 + lane];
    const float mu0 = s0 / safe, mu1 = s1 / safe;
    float msq = mu0 * mu0 + mu1 * mu1;
#pragma unroll
    for (int off = 1; off < 64; off <<= 1) msq += __shfl_xor(msq, off);
    if (lane == 0) {
      const float sq = ws[C * D + C + c];
      const float ssd = sq - n * msq;
      const float pc = ssd / safe;
      const bool valid = n > 1.f;
      sPer[c] = valid ? pc : 0.f;
      sValid[c] = valid ? 1.f : 0.f;
    }
  }
  __syncthreads();
  if (tid == 0) {
    float proto = 0.f, nv = 0.f;
    for (int c = 0; c < C; ++c) { proto += sPer[c]; nv += sValid[c]; }
    proto /= fmaxf(nv, 1.f);
    const float ce = ws[C * D + 2 * C] / (float)N_ROWS;
    out[0] = 0.5f * ce + 0.5f * proto;
  }
}

extern "C" void kernel_launch(void* const* d_in, const int* in_sizes, int n_in,
                              void* d_out, int out_size, void* d_ws, size_t ws_size,
                              hipStream_t stream) {
  const float* emb = (const float*)d_in[0];
  const float* logits = (const float*)d_in[1];
  const int* labels = (const int*)d_in[2];
  float* ws = (float*)d_ws;
  float* out = (float*)d_out;

  hipMemsetAsync(ws, 0, WS_FLOATS * sizeof(float), stream);
  proto_main<<<BLOCKS, THREADS, 0, stream>>>(emb, logits, labels, ws);
  proto_final<<<1, 256, 0, stream>>>(ws, out);
}

// Round 2
// 201.825 us; speedup vs baseline: 1.3065x; 1.3065x over previous
//
#include <hip/hip_runtime.h>
#include <math.h>

#define N_ROWS 262144
#define D 128
#define C 64
#define CD (C * D)
#define BLOCKS 1024
#define THREADS 512
#define WAVES 8
#define ROWS_PER_BLOCK (N_ROWS / BLOCKS)        // 256
#define ROWS_PER_WAVE (ROWS_PER_BLOCK / WAVES)  // 32
#define ITERS (ROWS_PER_WAVE / 4)               // 8

// replica slot (floats): [0,CD) sums | [CD,CD+C) cnt | [CD+C,CD+2C) sq | [CD+2C] ce
#define SLOT 8448

__global__ __launch_bounds__(THREADS, 8) void proto_main(
    const float* __restrict__ emb, const float* __restrict__ logits,
    const int* __restrict__ labels, float* __restrict__ ws, int rmask) {
  __shared__ float sSums[CD];
  __shared__ float sCnt[C];
  __shared__ float sSq[C];
  __shared__ float sCe;

  const int tid = threadIdx.x;
  for (int i = tid; i < CD; i += THREADS) sSums[i] = 0.f;
  if (tid < C) { sCnt[tid] = 0.f; sSq[tid] = 0.f; }
  if (tid == 0) sCe = 0.f;
  __syncthreads();

  const int wave = tid >> 6, lane = tid & 63;
  const int g = lane >> 4, lp = lane & 15;  // 4 groups of 16 lanes; group g owns one row
  float ce_acc = 0.f;
  const int rowBase = blockIdx.x * ROWS_PER_BLOCK + wave * ROWS_PER_WAVE;

  for (int it = 0; it < ITERS; ++it) {
    const int row = rowBase + it * 4 + g;
    const int lab = labels[row];

    // ---- embedding: lane lp owns dims [lp*8, lp*8+8) of its group's row ----
    const float* ep = emb + (size_t)row * D + lp * 8;
    const float4 ea = *(const float4*)ep;
    const float4 eb = *(const float4*)(ep + 4);
    float ss = ea.x * ea.x + ea.y * ea.y + ea.z * ea.z + ea.w * ea.w +
               eb.x * eb.x + eb.y * eb.y + eb.z * eb.z + eb.w * eb.w;
    ss += __shfl_xor(ss, 1);
    ss += __shfl_xor(ss, 2);
    ss += __shfl_xor(ss, 4);
    ss += __shfl_xor(ss, 8);
    const float inv = 1.0f / fmaxf(sqrtf(ss), 1e-12f);

    // ---- cross-entropy: lane lp owns logit cols [lp*4, lp*4+4) ----
    const float4 t4 = *(const float4*)(logits + (size_t)row * C + lp * 4);
    float p = __expf(t4.x) + __expf(t4.y) + __expf(t4.z) + __expf(t4.w);
    float tl = 0.f;
    if ((lab >> 2) == lp) {
      const int k = lab & 3;
      tl = k == 0 ? t4.x : k == 1 ? t4.y : k == 2 ? t4.z : t4.w;
    }
    p += __shfl_xor(p, 1);  tl += __shfl_xor(tl, 1);
    p += __shfl_xor(p, 2);  tl += __shfl_xor(tl, 2);
    p += __shfl_xor(p, 4);  tl += __shfl_xor(tl, 4);
    p += __shfl_xor(p, 8);  tl += __shfl_xor(tl, 8);

    if (lp == 0) {
      ce_acc += __logf(p) - tl;
      atomicAdd(&sCnt[lab], 1.f);
      atomicAdd(&sSq[lab], ss * inv * inv);
    }

    // ---- class sums. dim d = lp*8+j stored at transposed slot j*16+lp:
    // banks per instr = 16 distinct (4-way across groups); finalize only needs
    // sum over all slots so the permutation never needs inverting.
    const int cb = lab * D + lp;
    atomicAdd(&sSums[cb + 0],   ea.x * inv);
    atomicAdd(&sSums[cb + 16],  ea.y * inv);
    atomicAdd(&sSums[cb + 32],  ea.z * inv);
    atomicAdd(&sSums[cb + 48],  ea.w * inv);
    atomicAdd(&sSums[cb + 64],  eb.x * inv);
    atomicAdd(&sSums[cb + 80],  eb.y * inv);
    atomicAdd(&sSums[cb + 96],  eb.z * inv);
    atomicAdd(&sSums[cb + 112], eb.w * inv);
  }
  if (lp == 0) atomicAdd(&sCe, ce_acc);
  __syncthreads();

  // ---- flush block partials into one of R replica accumulators ----
  float* rep = ws + (size_t)(blockIdx.x & rmask) * SLOT;
  const int rot = (blockIdx.x * 997) & (CD - 1);
  for (int i = tid; i < CD; i += THREADS) {
    const int j = (i + rot) & (CD - 1);
    atomicAdd(&rep[j], sSums[j]);
  }
  if (tid < C) atomicAdd(&rep[CD + tid], sCnt[tid]);
  else if (tid < 2 * C) atomicAdd(&rep[CD + C + (tid - C)], sSq[tid - C]);
  else if (tid == 2 * C) atomicAdd(&rep[CD + 2 * C], sCe);
}

__global__ __launch_bounds__(128) void proto_class(const float* __restrict__ ws,
                                                   int nrep, float* __restrict__ res) {
  const int c = blockIdx.x, t = threadIdx.x;  // t = permuted dim slot in [0,128)
  float s = 0.f, n = 0.f, sq = 0.f;
  for (int r = 0; r < nrep; ++r) {
    const float* rep = ws + (size_t)r * SLOT;
    s += rep[c * D + t];
    n += rep[CD + c];
    sq += rep[CD + C + c];
  }
  const float safe = fmaxf(n, 1.f);
  const float mu = s / safe;
  float msq = mu * mu;
#pragma unroll
  for (int off = 1; off < 64; off <<= 1) msq += __shfl_xor(msq, off);
  __shared__ float sP[2];
  if ((t & 63) == 0) sP[t >> 6] = msq;
  __syncthreads();
  if (t == 0) {
    const float m2 = sP[0] + sP[1];
    const float ssd = sq - n * m2;
    const bool valid = n > 1.f;
    res[c] = valid ? ssd / safe : 0.f;
    res[C + c] = valid ? 1.f : 0.f;
  }
}

__global__ __launch_bounds__(64) void proto_final(const float* __restrict__ ws,
                                                  const float* __restrict__ res,
                                                  int nrep, float* __restrict__ out) {
  const int t = threadIdx.x;
  float pc = res[t], v = res[C + t];
#pragma unroll
  for (int off = 1; off < 64; off <<= 1) { pc += __shfl_xor(pc, off); v += __shfl_xor(v, off); }
  if (t == 0) {
    float ce = 0.f;
    for (int r = 0; r < nrep; ++r) ce += ws[(size_t)r * SLOT + CD + 2 * C];
    ce /= (float)N_ROWS;
    out[0] = 0.5f * ce + 0.5f * (pc / fmaxf(v, 1.f));
  }
}

extern "C" void kernel_launch(void* const* d_in, const int* in_sizes, int n_in,
                              void* d_out, int out_size, void* d_ws, size_t ws_size,
                              hipStream_t stream) {
  const float* emb = (const float*)d_in[0];
  const float* logits = (const float*)d_in[1];
  const int* labels = (const int*)d_in[2];
  float* ws = (float*)d_ws;
  float* out = (float*)d_out;

  int R = 8;
  while (R > 1 && (size_t)(R * SLOT + 2 * C) * sizeof(float) > ws_size) R >>= 1;
  float* res = ws + (size_t)R * SLOT;

  hipMemsetAsync(ws, 0, (size_t)R * SLOT * sizeof(float), stream);
  proto_main<<<BLOCKS, THREADS, 0, stream>>>(emb, logits, labels, ws, R - 1);
  proto_class<<<C, 128, 0, stream>>>(ws, R, res);
  proto_final<<<1, 64, 0, stream>>>(ws, res, R, out);
}